// Round 2
// baseline (279.185 us; speedup 1.0000x reference)
//
#include <hip/hip_runtime.h>
#include <math.h>

// DraftSampler: B=256 rows, V=128000 vocab.
// out[row] = (t==0) ? argmax(logits[row]) : argmax(exp(l/t - max(l)/t) / (noise + 1e-10))
// (softmax denominator S dropped: positive per-row constant, order-preserving)

__device__ __forceinline__ void amax_combine(float& v, int& i, float ov, int oi) {
    // prefer larger value; on exact tie prefer smaller index (jnp.argmax first-occurrence)
    if (ov > v || (ov == v && oi < i)) { v = ov; i = oi; }
}

__global__ __launch_bounds__(1024) void draft_sampler_kernel(
    const float* __restrict__ logits,
    const float* __restrict__ temps,
    const float* __restrict__ noise,
    int* __restrict__ out,
    int V)
{
    const int row = blockIdx.x;
    const int tid = threadIdx.x;
    const int nthr = blockDim.x;
    const int lane = tid & 63;
    const int wid  = tid >> 6;
    const int nwaves = nthr >> 6;

    const size_t base = (size_t)row * (size_t)V;
    const float4* l4 = (const float4*)(logits + base);
    const int n4 = V >> 2;

    __shared__ float sv[16];
    __shared__ int   si[16];

    // ---------- Phase 1: max + argmax of logits (greedy token; M for softmax) ----------
    float bv = -INFINITY; int bi = 0x7fffffff;
    for (int j = tid; j < n4; j += nthr) {
        float4 x = l4[j];
        int k = j << 2;
        if (x.x > bv) { bv = x.x; bi = k; }
        if (x.y > bv) { bv = x.y; bi = k + 1; }
        if (x.z > bv) { bv = x.z; bi = k + 2; }
        if (x.w > bv) { bv = x.w; bi = k + 3; }
    }
    // wave reduce (64 lanes)
    #pragma unroll
    for (int off = 32; off > 0; off >>= 1) {
        float ov = __shfl_down(bv, off, 64);
        int   oi = __shfl_down(bi, off, 64);
        amax_combine(bv, bi, ov, oi);
    }
    if (lane == 0) { sv[wid] = bv; si[wid] = bi; }
    __syncthreads();
    if (tid == 0) {
        float gv = sv[0]; int gi = si[0];
        for (int w = 1; w < nwaves; ++w) amax_combine(gv, gi, sv[w], si[w]);
        sv[0] = gv; si[0] = gi;
    }
    __syncthreads();
    const float gmax = sv[0];
    const int   gidx = si[0];

    // ---------- Phase 2: sampled token ----------
    const float t = temps[row];
    if (t == 0.0f) {
        if (tid == 0) out[row] = gidx;
        return;
    }
    const float xm = gmax / t;   // fp32 div is monotone => equals max_i fl(l_i/t)
    const float4* z4 = (const float4*)(noise + base);

    float rv = -INFINITY; int ri = 0x7fffffff;
    for (int j = tid; j < n4; j += nthr) {
        float4 x = l4[j];
        float4 z = z4[j];
        int k = j << 2;
        float r0 = expf(x.x / t - xm) / (z.x + 1e-10f);
        float r1 = expf(x.y / t - xm) / (z.y + 1e-10f);
        float r2 = expf(x.z / t - xm) / (z.z + 1e-10f);
        float r3 = expf(x.w / t - xm) / (z.w + 1e-10f);
        if (r0 > rv) { rv = r0; ri = k; }
        if (r1 > rv) { rv = r1; ri = k + 1; }
        if (r2 > rv) { rv = r2; ri = k + 2; }
        if (r3 > rv) { rv = r3; ri = k + 3; }
    }
    #pragma unroll
    for (int off = 32; off > 0; off >>= 1) {
        float ov = __shfl_down(rv, off, 64);
        int   oi = __shfl_down(ri, off, 64);
        amax_combine(rv, ri, ov, oi);
    }
    __syncthreads();   // protect sv/si reuse
    if (lane == 0) { sv[wid] = rv; si[wid] = ri; }
    __syncthreads();
    if (tid == 0) {
        float gv = sv[0]; int gi = si[0];
        for (int w = 1; w < nwaves; ++w) amax_combine(gv, gi, sv[w], si[w]);
        out[row] = gi;
    }
}

extern "C" void kernel_launch(void* const* d_in, const int* in_sizes, int n_in,
                              void* d_out, int out_size, void* d_ws, size_t ws_size,
                              hipStream_t stream) {
    const float* logits = (const float*)d_in[0];
    const float* temps  = (const float*)d_in[1];
    const float* noise  = (const float*)d_in[2];
    int* out = (int*)d_out;

    const int B = in_sizes[1];              // 256
    const int V = in_sizes[0] / B;          // 128000

    draft_sampler_kernel<<<B, 1024, 0, stream>>>(logits, temps, noise, out, V);
}